// Round 10
// baseline (1871.578 us; speedup 1.0000x reference)
//
#include <hip/hip_runtime.h>
#include <hip/hip_bf16.h>
#include <math.h>

#define BB 8
#define NN 4096
#define NIN 64
#define NOUTF 128
#define KNB 32
#define MM 1024
#define DIM 68
#define CAP 320

typedef float f32x2 __attribute__((ext_vector_type(2)));

// Separate single-instruction VOP3P asm helpers (R7 style): the compiler can
// interleave independent j-iterations between them (critical at low occupancy).
__device__ __forceinline__ f32x2 pk_add(f32x2 a, f32x2 b)
{
    f32x2 d;
    asm("v_pk_add_f32 %0, %1, %2" : "=v"(d) : "v"(a), "v"(b));
    return d;
}
__device__ __forceinline__ f32x2 pk_mul(f32x2 a, f32x2 b)
{
    f32x2 d;
    asm("v_pk_mul_f32 %0, %1, %2" : "=v"(d) : "v"(a), "v"(b));
    return d;
}

__device__ __forceinline__ f32x2 pkmax(f32x2 a, f32x2 b)
{
    f32x2 r; r.x = fmaxf(a.x, b.x); r.y = fmaxf(a.y, b.y); return r;
}

template <int CTRL>
__device__ __forceinline__ float dppmax(float v)
{
    int m = __builtin_amdgcn_update_dpp(__float_as_int(v), __float_as_int(v),
                                        CTRL, 0xF, 0xF, false);
    return fmaxf(v, __int_as_float(m));
}

// ---------------------------------------------------------------------------
// fps_a: exact R7 replica. 256 threads (4 waves, 1 wave/SIMD), 16 pts/thread.
// ---------------------------------------------------------------------------
__global__ __launch_bounds__(256) void fps_a(
    const float* __restrict__ pos,
    int* __restrict__ idx_ws,
    float* __restrict__ out_pos_s, float* __restrict__ out_idx)
{
#pragma clang fp contract(off)
    __shared__ float4 posL[NN];
    __shared__ f32x2  slot[2][4];

    const int b    = blockIdx.x;
    const int tid  = threadIdx.x;
    const int wv   = tid >> 6;
    const int lane = tid & 63;
    const float* pb = pos + (size_t)b * NN * 3;

    f32x2 X[8], Y[8], Z[8], D[8];
#pragma unroll
    for (int j = 0; j < 8; ++j) {
        int pA = tid * 16 + 2 * j;
        X[j].x = pb[pA * 3 + 0]; X[j].y = pb[pA * 3 + 3];
        Y[j].x = pb[pA * 3 + 1]; Y[j].y = pb[pA * 3 + 4];
        Z[j].x = pb[pA * 3 + 2]; Z[j].y = pb[pA * 3 + 5];
        D[j].x = INFINITY;       D[j].y = INFINITY;
    }
#pragma unroll
    for (int j = 0; j < 16; ++j) {
        int p2 = tid + 256 * j;
        posL[p2] = make_float4(pb[p2 * 3 + 0], pb[p2 * 3 + 1],
                               pb[p2 * 3 + 2], 0.0f);
    }
    __syncthreads();

    int   last = 0;
    float lx = pb[0], ly = pb[1], lz = pb[2];

#pragma unroll 2
    for (int t = 0; t < MM; ++t) {
        if (tid == 0) {
            int base = b * MM + t;
            idx_ws[base]  = last;
            out_idx[base] = (float)last;
            out_pos_s[base * 3 + 0] = lx;
            out_pos_s[base * 3 + 1] = ly;
            out_pos_s[base * 3 + 2] = lz;
        }

        float nx = -lx, ny = -ly, nz = -lz;
        f32x2 nx2; nx2.x = nx; nx2.y = nx;
        f32x2 ny2; ny2.x = ny; ny2.y = ny;
        f32x2 nz2; nz2.x = nz; nz2.y = nz;

#pragma unroll
        for (int j = 0; j < 8; ++j) {
            f32x2 dx = pk_add(X[j], nx2);
            f32x2 dy = pk_add(Y[j], ny2);
            f32x2 dz = pk_add(Z[j], nz2);
            f32x2 xx = pk_mul(dx, dx);
            f32x2 yy = pk_mul(dy, dy);
            f32x2 zz = pk_mul(dz, dz);
            f32x2 s  = pk_add(pk_add(xx, yy), zz);
            D[j].x = fminf(D[j].x, s.x);
            D[j].y = fminf(D[j].y, s.y);
        }
        f32x2 m0 = pkmax(pkmax(D[0], D[1]), pkmax(D[2], D[3]));
        f32x2 m1 = pkmax(pkmax(D[4], D[5]), pkmax(D[6], D[7]));
        f32x2 mm = pkmax(m0, m1);
        float bv = fmaxf(mm.x, mm.y);

        int k0 = (D[0].x == bv) ? 0  : ((D[0].y == bv) ? 1  : 16);
        int k1 = (D[1].x == bv) ? 2  : ((D[1].y == bv) ? 3  : 16);
        int k2 = (D[2].x == bv) ? 4  : ((D[2].y == bv) ? 5  : 16);
        int k3 = (D[3].x == bv) ? 6  : ((D[3].y == bv) ? 7  : 16);
        int k4 = (D[4].x == bv) ? 8  : ((D[4].y == bv) ? 9  : 16);
        int k5 = (D[5].x == bv) ? 10 : ((D[5].y == bv) ? 11 : 16);
        int k6 = (D[6].x == bv) ? 12 : ((D[6].y == bv) ? 13 : 16);
        int k7 = (D[7].x == bv) ? 14 : ((D[7].y == bv) ? 15 : 16);
        k0 = min(k0, k4); k1 = min(k1, k5); k2 = min(k2, k6); k3 = min(k3, k7);
        k0 = min(k0, k2); k1 = min(k1, k3);
        int kmin = min(k0, k1);
        int p_cand = tid * 16 + kmin;

        float r = bv;
        r = dppmax<0x111>(r);
        r = dppmax<0x112>(r);
        r = dppmax<0x114>(r);
        r = dppmax<0x118>(r);
        r = dppmax<0x142>(r);
        r = dppmax<0x143>(r);
        float wmax = __int_as_float(__builtin_amdgcn_readlane(__float_as_int(r), 63));

        unsigned long long msk = __ballot(bv == wmax);
        int wl = __ffsll((long long)msk) - 1;
        int pwin_wave = __builtin_amdgcn_readlane(p_cand, wl);

        const int p_ = t & 1;
        if (lane == 0) {
            f32x2 sv; sv.x = wmax; sv.y = __int_as_float(pwin_wave);
            slot[p_][wv] = sv;
        }
        __syncthreads();

        f32x2 s0 = slot[p_][0], s1 = slot[p_][1];
        f32x2 s2 = slot[p_][2], s3 = slot[p_][3];
        float cv = s0.x; int ci = __float_as_int(s0.y);
        {
            int i1 = __float_as_int(s1.y);
            bool bt = (s1.x > cv) || (s1.x == cv && i1 < ci);
            cv = bt ? s1.x : cv; ci = bt ? i1 : ci;
        }
        {
            int i2 = __float_as_int(s2.y);
            bool bt = (s2.x > cv) || (s2.x == cv && i2 < ci);
            cv = bt ? s2.x : cv; ci = bt ? i2 : ci;
        }
        {
            int i3 = __float_as_int(s3.y);
            bool bt = (s3.x > cv) || (s3.x == cv && i3 < ci);
            cv = bt ? s3.x : cv; ci = bt ? i3 : ci;
        }

        float4 cw = posL[ci];
        last = ci; lx = cw.x; ly = cw.y; lz = cw.z;
    }
}

// ---------------------------------------------------------------------------
// fps_b: same algorithm, 512 threads (8 waves, 2 waves/SIMD), 8 pts/thread,
// slim 8-slot merge. Output bit-identical to fps_a.
// ---------------------------------------------------------------------------
__global__ __launch_bounds__(512) void fps_b(
    const float* __restrict__ pos,
    int* __restrict__ idx_ws,
    float* __restrict__ out_pos_s, float* __restrict__ out_idx)
{
#pragma clang fp contract(off)
    __shared__ float4 posL[NN];
    __shared__ f32x2  slot[2][8];

    const int b    = blockIdx.x;
    const int tid  = threadIdx.x;
    const int wv   = tid >> 6;
    const int lane = tid & 63;
    const float* pb = pos + (size_t)b * NN * 3;

    // 8 consecutive points per thread: p = tid*8 + k.
    f32x2 X[4], Y[4], Z[4], D[4];
#pragma unroll
    for (int j = 0; j < 4; ++j) {
        int pA = tid * 8 + 2 * j;
        X[j].x = pb[pA * 3 + 0]; X[j].y = pb[pA * 3 + 3];
        Y[j].x = pb[pA * 3 + 1]; Y[j].y = pb[pA * 3 + 4];
        Z[j].x = pb[pA * 3 + 2]; Z[j].y = pb[pA * 3 + 5];
        D[j].x = INFINITY;       D[j].y = INFINITY;
    }
#pragma unroll
    for (int j = 0; j < 8; ++j) {
        int p2 = tid + 512 * j;
        posL[p2] = make_float4(pb[p2 * 3 + 0], pb[p2 * 3 + 1],
                               pb[p2 * 3 + 2], 0.0f);
    }
    __syncthreads();

    int   last = 0;
    float lx = pb[0], ly = pb[1], lz = pb[2];

#pragma unroll 2
    for (int t = 0; t < MM; ++t) {
        if (tid == 0) {
            int base = b * MM + t;
            idx_ws[base]  = last;
            out_idx[base] = (float)last;
            out_pos_s[base * 3 + 0] = lx;
            out_pos_s[base * 3 + 1] = ly;
            out_pos_s[base * 3 + 2] = lz;
        }

        float nx = -lx, ny = -ly, nz = -lz;
        f32x2 nx2; nx2.x = nx; nx2.y = nx;
        f32x2 ny2; ny2.x = ny; ny2.y = ny;
        f32x2 nz2; nz2.x = nz; nz2.y = nz;

#pragma unroll
        for (int j = 0; j < 4; ++j) {
            f32x2 dx = pk_add(X[j], nx2);
            f32x2 dy = pk_add(Y[j], ny2);
            f32x2 dz = pk_add(Z[j], nz2);
            f32x2 xx = pk_mul(dx, dx);
            f32x2 yy = pk_mul(dy, dy);
            f32x2 zz = pk_mul(dz, dz);
            f32x2 s  = pk_add(pk_add(xx, yy), zz);
            D[j].x = fminf(D[j].x, s.x);
            D[j].y = fminf(D[j].y, s.y);
        }
        f32x2 mm = pkmax(pkmax(D[0], D[1]), pkmax(D[2], D[3]));
        float bv = fmaxf(mm.x, mm.y);

        int k0 = (D[0].x == bv) ? 0 : ((D[0].y == bv) ? 1 : 8);
        int k1 = (D[1].x == bv) ? 2 : ((D[1].y == bv) ? 3 : 8);
        int k2 = (D[2].x == bv) ? 4 : ((D[2].y == bv) ? 5 : 8);
        int k3 = (D[3].x == bv) ? 6 : ((D[3].y == bv) ? 7 : 8);
        k0 = min(k0, k2); k1 = min(k1, k3);
        int kmin = min(k0, k1);
        int p_cand = tid * 8 + kmin;

        float r = bv;
        r = dppmax<0x111>(r);
        r = dppmax<0x112>(r);
        r = dppmax<0x114>(r);
        r = dppmax<0x118>(r);
        r = dppmax<0x142>(r);
        r = dppmax<0x143>(r);
        float wmax = __int_as_float(__builtin_amdgcn_readlane(__float_as_int(r), 63));

        unsigned long long msk = __ballot(bv == wmax);
        int wl = __ffsll((long long)msk) - 1;
        int pwin_wave = __builtin_amdgcn_readlane(p_cand, wl);

        const int p_ = t & 1;
        if (lane == 0) {
            f32x2 sv; sv.x = wmax; sv.y = __int_as_float(pwin_wave);
            slot[p_][wv] = sv;
        }
        __syncthreads();

        // slim 8-slot merge: 4x b128 reads (pairs), 7 dependent lex-selects
        float cv; int ci;
        {
            f32x2 s0 = slot[p_][0];
            cv = s0.x; ci = __float_as_int(s0.y);
        }
#pragma unroll
        for (int w = 1; w < 8; ++w) {
            f32x2 sw = slot[p_][w];
            int iw = __float_as_int(sw.y);
            bool bt = (sw.x > cv) || (sw.x == cv && iw < ci);
            cv = bt ? sw.x : cv; ci = bt ? iw : ci;
        }

        float4 cw = posL[ci];
        last = ci; lx = cw.x; ly = cw.y; lz = cw.z;
    }
}

// ---------------------------------------------------------------------------
// Kernel 2: radius search + exact K-smallest selection. One wave per center.
// ---------------------------------------------------------------------------
__global__ __launch_bounds__(256) void radius_kernel(
    const float* __restrict__ pos,
    const float* __restrict__ pos_s,
    int* __restrict__ nbr_ws, int* __restrict__ nvalid_ws)
{
    __shared__ float d2L[4][CAP];
    __shared__ int   idL[4][CAP];
    __shared__ int   cntL[4];

    const int wv = threadIdx.x >> 6, lane = threadIdx.x & 63;
    const int c = blockIdx.x * 4 + wv;
    const int b = c >> 10;
    const float RSQ = 0.0225f;

    if (lane == 0) cntL[wv] = 0;

    float cx = pos_s[c * 3 + 0];
    float cy = pos_s[c * 3 + 1];
    float cz = pos_s[c * 3 + 2];
    const float* pb = pos + (size_t)b * NN * 3;

    for (int it = 0; it < NN / 64; ++it) {
        int p = it * 64 + lane;
        float dx = __fsub_rn(cx, pb[p * 3 + 0]);
        float dy = __fsub_rn(cy, pb[p * 3 + 1]);
        float dz = __fsub_rn(cz, pb[p * 3 + 2]);
        float d2 = __fadd_rn(__fadd_rn(__fmul_rn(dx, dx), __fmul_rn(dy, dy)),
                             __fmul_rn(dz, dz));
        if (d2 <= RSQ) {
            int slot = atomicAdd(&cntL[wv], 1);
            if (slot < CAP) { d2L[wv][slot] = d2; idL[wv][slot] = p; }
        }
    }
    int n = cntL[wv];
    if (n > CAP) n = CAP;

    if (n <= KNB) {
        if (lane == 0) nvalid_ws[c] = n;
        if (lane < n) nbr_ws[c * KNB + lane] = idL[wv][lane];
    } else {
        if (lane == 0) nvalid_ws[c] = KNB;
        for (int a = lane; a < n; a += 64) {
            float da = d2L[wv][a]; int ia = idL[wv][a];
            int r = 0;
            for (int jj = 0; jj < n; ++jj) {
                float dj = d2L[wv][jj]; int ij = idL[wv][jj];
                r += (dj < da || (dj == da && ij < ia)) ? 1 : 0;
            }
            if (r < KNB) nbr_ws[c * KNB + r] = ia;
        }
    }
}

// ---------------------------------------------------------------------------
// Kernel 3: message build -> 68x68 MLP x2 -> masked max-agg -> 68x128 matvec.
// ---------------------------------------------------------------------------
__device__ __forceinline__ float angle3(float ax, float ay, float az,
                                        float bx, float by, float bz)
{
    float cx = ay * bz - az * by;
    float cy = az * bx - ax * bz;
    float cz = ax * by - ay * bx;
    float cn = sqrtf(cx * cx + cy * cy + cz * cz);
    float dt = ax * bx + ay * by + az * bz;
    return atan2f(cn, dt);
}

__device__ __forceinline__ float4 fma4(float m, float4 w, float4 a)
{
    a.x = fmaf(m, w.x, a.x);
    a.y = fmaf(m, w.y, a.y);
    a.z = fmaf(m, w.z, a.z);
    a.w = fmaf(m, w.w, a.w);
    return a;
}

__device__ __forceinline__ void layer_pass(const float* __restrict__ inL,
                                           const float* __restrict__ Ws,
                                           const float* __restrict__ bs,
                                           float* __restrict__ outL, int t)
{
    const int e = t & 63, wvi = t >> 6;
    const bool has5 = (wvi == 0);
    const int j0 = wvi * 4, j1 = (wvi + 4) * 4, j2 = (wvi + 8) * 4,
              j3 = (wvi + 12) * 4, j4 = 64;

    float4 a0 = *reinterpret_cast<const float4*>(bs + j0);
    float4 a1 = *reinterpret_cast<const float4*>(bs + j1);
    float4 a2 = *reinterpret_cast<const float4*>(bs + j2);
    float4 a3 = *reinterpret_cast<const float4*>(bs + j3);
    float4 a4 = has5 ? *reinterpret_cast<const float4*>(bs + j4)
                     : make_float4(0.f, 0.f, 0.f, 0.f);

    const float* row = inL + e * 69;
#pragma unroll 4
    for (int i = 0; i < DIM; ++i) {
        float m = row[i];
        const float* wr = Ws + i * DIM;
        a0 = fma4(m, *reinterpret_cast<const float4*>(wr + j0), a0);
        a1 = fma4(m, *reinterpret_cast<const float4*>(wr + j1), a1);
        a2 = fma4(m, *reinterpret_cast<const float4*>(wr + j2), a2);
        a3 = fma4(m, *reinterpret_cast<const float4*>(wr + j3), a3);
        if (has5) a4 = fma4(m, *reinterpret_cast<const float4*>(wr + j4), a4);
    }

    float* orow = outL + e * 69;
    orow[j0 + 0] = fmaxf(a0.x, 0.f); orow[j0 + 1] = fmaxf(a0.y, 0.f);
    orow[j0 + 2] = fmaxf(a0.z, 0.f); orow[j0 + 3] = fmaxf(a0.w, 0.f);
    orow[j1 + 0] = fmaxf(a1.x, 0.f); orow[j1 + 1] = fmaxf(a1.y, 0.f);
    orow[j1 + 2] = fmaxf(a1.z, 0.f); orow[j1 + 3] = fmaxf(a1.w, 0.f);
    orow[j2 + 0] = fmaxf(a2.x, 0.f); orow[j2 + 1] = fmaxf(a2.y, 0.f);
    orow[j2 + 2] = fmaxf(a2.z, 0.f); orow[j2 + 3] = fmaxf(a2.w, 0.f);
    orow[j3 + 0] = fmaxf(a3.x, 0.f); orow[j3 + 1] = fmaxf(a3.y, 0.f);
    orow[j3 + 2] = fmaxf(a3.z, 0.f); orow[j3 + 3] = fmaxf(a3.w, 0.f);
    if (has5) {
        orow[64] = fmaxf(a4.x, 0.f); orow[65] = fmaxf(a4.y, 0.f);
        orow[66] = fmaxf(a4.z, 0.f); orow[67] = fmaxf(a4.w, 0.f);
    }
}

__global__ __launch_bounds__(256) void mlp_kernel(
    const float* __restrict__ x, const float* __restrict__ pos,
    const float* __restrict__ norm,
    const float* __restrict__ W1, const float* __restrict__ b1,
    const float* __restrict__ W2, const float* __restrict__ b2,
    const float* __restrict__ W3, const float* __restrict__ b3,
    const int* __restrict__ idx_ws, const float* __restrict__ pos_s,
    const int* __restrict__ nbr_ws, const int* __restrict__ nvalid_ws,
    float* __restrict__ out)
{
    __shared__ alignas(16) float W1s[DIM * DIM];
    __shared__ alignas(16) float W2s[DIM * DIM];
    __shared__ alignas(16) float b1s[DIM];
    __shared__ alignas(16) float b2s[DIM];
    __shared__ float msgL[64 * 69];
    __shared__ float h1L[64 * 69];
    __shared__ float aggL[2 * DIM];
    __shared__ int   nvL[2], jLs[64];

    const int t = threadIdx.x;
    const int cg0 = blockIdx.x * 2;

    for (int u = t; u < DIM * DIM; u += 256) { W1s[u] = W1[u]; W2s[u] = W2[u]; }
    if (t < DIM) { b1s[t] = b1[t]; b2s[t] = b2[t]; }
    if (t < 2) nvL[t] = min(nvalid_ws[cg0 + t], KNB);
    __syncthreads();

    const int e = t & 63, fc = t >> 6;
    const int lc = e >> 5, slot = e & 31;
    const int c = cg0 + lc;
    const int b = c >> 10;

    if (fc == 0) {
        int nv = nvL[lc];
        jLs[e] = (slot < nv) ? nbr_ws[c * KNB + slot] : 0;
    }
    __syncthreads();

    const int j = jLs[e];
    {
        const float* xj = x + ((size_t)b * NN + j) * NIN + fc * 16;
#pragma unroll
        for (int r = 0; r < 4; ++r) {
            float4 v = *reinterpret_cast<const float4*>(xj + r * 4);
            msgL[e * 69 + fc * 16 + r * 4 + 0] = v.x;
            msgL[e * 69 + fc * 16 + r * 4 + 1] = v.y;
            msgL[e * 69 + fc * 16 + r * 4 + 2] = v.z;
            msgL[e * 69 + fc * 16 + r * 4 + 3] = v.w;
        }
    }
    if (fc == 0) {
        float pix = pos_s[c * 3 + 0];
        float piy = pos_s[c * 3 + 1];
        float piz = pos_s[c * 3 + 2];
        int ic = idx_ws[c];
        const float* pj_ = pos  + ((size_t)b * NN + j) * 3;
        const float* nj_ = norm + ((size_t)b * NN + j) * 3;
        const float* ni_ = norm + ((size_t)b * NN + ic) * 3;
        float dx = pj_[0] - pix, dy = pj_[1] - piy, dz = pj_[2] - piz;
        float nix = ni_[0], niy = ni_[1], niz = ni_[2];
        float njx = nj_[0], njy = nj_[1], njz = nj_[2];
        msgL[e * 69 + 64] = sqrtf(dx * dx + dy * dy + dz * dz);
        msgL[e * 69 + 65] = angle3(nix, niy, niz, dx, dy, dz);
        msgL[e * 69 + 66] = angle3(njx, njy, njz, dx, dy, dz);
        msgL[e * 69 + 67] = angle3(nix, niy, niz, njx, njy, njz);
    }
    __syncthreads();

    layer_pass(msgL, W1s, b1s, h1L, t);
    __syncthreads();
    layer_pass(h1L, W2s, b2s, msgL, t);
    __syncthreads();

    if (t < 2 * DIM) {
        int cc = t / DIM, jf = t % DIM;
        int nv = nvL[cc];
        float v = -INFINITY;
        for (int s = 0; s < nv; ++s)
            v = fmaxf(v, msgL[(cc * 32 + s) * 69 + jf]);
        aggL[cc * DIM + jf] = v;
    }
    __syncthreads();

    {
        int cc = t >> 7, o = t & 127;
        int cgl = cg0 + cc;
        float acc = b3[o];
#pragma unroll 4
        for (int i = 0; i < DIM; ++i)
            acc = fmaf(aggL[cc * DIM + i], W3[i * NOUTF + o], acc);
        out[(size_t)cgl * NOUTF + o] = fmaxf(acc, 0.0f);
    }
}

// ---------------------------------------------------------------------------
extern "C" void kernel_launch(void* const* d_in, const int* in_sizes, int n_in,
                              void* d_out, int out_size, void* d_ws, size_t ws_size,
                              hipStream_t stream)
{
    const float* x    = (const float*)d_in[0];
    const float* pos  = (const float*)d_in[1];
    const float* norm = (const float*)d_in[2];
    const float* W1 = (const float*)d_in[4];
    const float* b1 = (const float*)d_in[5];
    const float* W2 = (const float*)d_in[6];
    const float* b2 = (const float*)d_in[7];
    const float* W3 = (const float*)d_in[8];
    const float* b3 = (const float*)d_in[9];

    float* out       = (float*)d_out;
    float* out_pos_s = out + (size_t)BB * MM * NOUTF;
    float* out_idx   = out_pos_s + (size_t)BB * MM * 3;

    char* ws = (char*)d_ws;
    int*   idx_ws    = (int*)ws;
    int*   nbr_ws    = (int*)(ws + 131072);
    int*   nvalid_ws = (int*)(ws + 131072 + (size_t)BB * MM * KNB * 4);

    // Within-probe A/B: identical outputs, rocprof times each separately.
    fps_a<<<dim3(BB), dim3(256), 0, stream>>>(pos, idx_ws, out_pos_s, out_idx);
    fps_b<<<dim3(BB), dim3(512), 0, stream>>>(pos, idx_ws, out_pos_s, out_idx);

    radius_kernel<<<dim3((BB * MM) / 4), dim3(256), 0, stream>>>(pos, out_pos_s,
                                                                 nbr_ws, nvalid_ws);
    mlp_kernel<<<dim3((BB * MM) / 2), dim3(256), 0, stream>>>(
        x, pos, norm, W1, b1, W2, b2, W3, b3,
        idx_ws, out_pos_s, nbr_ws, nvalid_ws, out);
}

// Round 11
// 956.770 us; speedup vs baseline: 1.9561x; 1.9561x over previous
//
#include <hip/hip_runtime.h>
#include <hip/hip_bf16.h>
#include <math.h>

#define BB 8
#define NN 4096
#define NIN 64
#define NOUTF 128
#define KNB 32
#define MM 1024
#define DIM 68
#define CAP 320

typedef float f32x2 __attribute__((ext_vector_type(2)));

// Separate single-instruction VOP3P asm helpers: compiler interleaves
// independent j-iterations between them (critical at 1 wave/SIMD).
__device__ __forceinline__ f32x2 pk_add(f32x2 a, f32x2 b)
{
    f32x2 d;
    asm("v_pk_add_f32 %0, %1, %2" : "=v"(d) : "v"(a), "v"(b));
    return d;
}
__device__ __forceinline__ f32x2 pk_mul(f32x2 a, f32x2 b)
{
    f32x2 d;
    asm("v_pk_mul_f32 %0, %1, %2" : "=v"(d) : "v"(a), "v"(b));
    return d;
}

__device__ __forceinline__ f32x2 pkmax(f32x2 a, f32x2 b)
{
    f32x2 r; r.x = fmaxf(a.x, b.x); r.y = fmaxf(a.y, b.y); return r;
}

template <int CTRL>
__device__ __forceinline__ float dppmax(float v)
{
    int m = __builtin_amdgcn_update_dpp(__float_as_int(v), __float_as_int(v),
                                        CTRL, 0xF, 0xF, false);
    return fmaxf(v, __int_as_float(m));
}

// ---------------------------------------------------------------------------
// Kernel 1: farthest point sampling. R7-winning structure (256 thr = 4 waves,
// 16 pts/thread, p = tid*16+k, max-only scan, DPP wave-max + ballot, 1 barrier,
// posL broadcast) with ONE change vs R7: no global stores inside the loop —
// samples buffered in LDS and flushed after (barrier drains vmcnt(0), so
// in-loop HBM stores stall all waves).
// Exact-match: contract off, (dx²+dy²)+dz² order, first-occurrence argmax.
// ---------------------------------------------------------------------------
__global__ __launch_bounds__(256) void fps_kernel(
    const float* __restrict__ pos,
    int* __restrict__ idx_ws,
    float* __restrict__ out_pos_s, float* __restrict__ out_idx)
{
#pragma clang fp contract(off)
    __shared__ float4 posL[NN];      // 64 KiB coords for winner broadcast
    __shared__ f32x2  slot[2][4];    // {val, idx-as-bits} per wave, dbuf
    __shared__ float4 emitP[MM];     // 16 KiB sample coords
    __shared__ int    emitI[MM];     // 4 KiB sample indices

    const int b    = blockIdx.x;
    const int tid  = threadIdx.x;
    const int wv   = tid >> 6;
    const int lane = tid & 63;
    const float* pb = pos + (size_t)b * NN * 3;

    f32x2 X[8], Y[8], Z[8], D[8];
#pragma unroll
    for (int j = 0; j < 8; ++j) {
        int pA = tid * 16 + 2 * j;
        X[j].x = pb[pA * 3 + 0]; X[j].y = pb[pA * 3 + 3];
        Y[j].x = pb[pA * 3 + 1]; Y[j].y = pb[pA * 3 + 4];
        Z[j].x = pb[pA * 3 + 2]; Z[j].y = pb[pA * 3 + 5];
        D[j].x = INFINITY;       D[j].y = INFINITY;
    }
#pragma unroll
    for (int j = 0; j < 16; ++j) {
        int p2 = tid + 256 * j;
        posL[p2] = make_float4(pb[p2 * 3 + 0], pb[p2 * 3 + 1],
                               pb[p2 * 3 + 2], 0.0f);
    }
    __syncthreads();

    int   last = 0;
    float lx = pb[0], ly = pb[1], lz = pb[2];

#pragma unroll 2
    for (int t = 0; t < MM; ++t) {
        // record current sample in LDS (no global traffic inside the loop)
        if (tid == 0) {
            emitP[t] = make_float4(lx, ly, lz, 0.0f);
            emitI[t] = last;
        }

        float nx = -lx, ny = -ly, nz = -lz;
        f32x2 nx2; nx2.x = nx; nx2.y = nx;
        f32x2 ny2; ny2.x = ny; ny2.y = ny;
        f32x2 nz2; nz2.x = nz; nz2.y = nz;

#pragma unroll
        for (int j = 0; j < 8; ++j) {
            f32x2 dx = pk_add(X[j], nx2);
            f32x2 dy = pk_add(Y[j], ny2);
            f32x2 dz = pk_add(Z[j], nz2);
            f32x2 xx = pk_mul(dx, dx);
            f32x2 yy = pk_mul(dy, dy);
            f32x2 zz = pk_mul(dz, dz);
            f32x2 s  = pk_add(pk_add(xx, yy), zz);
            D[j].x = fminf(D[j].x, s.x);
            D[j].y = fminf(D[j].y, s.y);
        }
        f32x2 m0 = pkmax(pkmax(D[0], D[1]), pkmax(D[2], D[3]));
        f32x2 m1 = pkmax(pkmax(D[4], D[5]), pkmax(D[6], D[7]));
        f32x2 mm = pkmax(m0, m1);
        float bv = fmaxf(mm.x, mm.y);

        int k0 = (D[0].x == bv) ? 0  : ((D[0].y == bv) ? 1  : 16);
        int k1 = (D[1].x == bv) ? 2  : ((D[1].y == bv) ? 3  : 16);
        int k2 = (D[2].x == bv) ? 4  : ((D[2].y == bv) ? 5  : 16);
        int k3 = (D[3].x == bv) ? 6  : ((D[3].y == bv) ? 7  : 16);
        int k4 = (D[4].x == bv) ? 8  : ((D[4].y == bv) ? 9  : 16);
        int k5 = (D[5].x == bv) ? 10 : ((D[5].y == bv) ? 11 : 16);
        int k6 = (D[6].x == bv) ? 12 : ((D[6].y == bv) ? 13 : 16);
        int k7 = (D[7].x == bv) ? 14 : ((D[7].y == bv) ? 15 : 16);
        k0 = min(k0, k4); k1 = min(k1, k5); k2 = min(k2, k6); k3 = min(k3, k7);
        k0 = min(k0, k2); k1 = min(k1, k3);
        int kmin = min(k0, k1);
        int p_cand = tid * 16 + kmin;

        float r = bv;
        r = dppmax<0x111>(r);
        r = dppmax<0x112>(r);
        r = dppmax<0x114>(r);
        r = dppmax<0x118>(r);
        r = dppmax<0x142>(r);
        r = dppmax<0x143>(r);
        float wmax = __int_as_float(__builtin_amdgcn_readlane(__float_as_int(r), 63));

        unsigned long long msk = __ballot(bv == wmax);
        int wl = __ffsll((long long)msk) - 1;
        int pwin_wave = __builtin_amdgcn_readlane(p_cand, wl);

        const int p_ = t & 1;
        if (lane == 0) {
            f32x2 sv; sv.x = wmax; sv.y = __int_as_float(pwin_wave);
            slot[p_][wv] = sv;
        }
        __syncthreads();   // drains only LDS now: no global ops pending

        f32x2 s0 = slot[p_][0], s1 = slot[p_][1];
        f32x2 s2 = slot[p_][2], s3 = slot[p_][3];
        float cv = s0.x; int ci = __float_as_int(s0.y);
        {
            int i1 = __float_as_int(s1.y);
            bool bt = (s1.x > cv) || (s1.x == cv && i1 < ci);
            cv = bt ? s1.x : cv; ci = bt ? i1 : ci;
        }
        {
            int i2 = __float_as_int(s2.y);
            bool bt = (s2.x > cv) || (s2.x == cv && i2 < ci);
            cv = bt ? s2.x : cv; ci = bt ? i2 : ci;
        }
        {
            int i3 = __float_as_int(s3.y);
            bool bt = (s3.x > cv) || (s3.x == cv && i3 < ci);
            cv = bt ? s3.x : cv; ci = bt ? i3 : ci;
        }

        float4 cw = posL[ci];
        last = ci; lx = cw.x; ly = cw.y; lz = cw.z;
    }

    __syncthreads();
    // flush buffered samples to global once
    for (int u = tid; u < MM; u += 256) {
        float4 rec = emitP[u];
        int    id  = emitI[u];
        int base = b * MM + u;
        idx_ws[base]  = id;
        out_idx[base] = (float)id;
        out_pos_s[base * 3 + 0] = rec.x;
        out_pos_s[base * 3 + 1] = rec.y;
        out_pos_s[base * 3 + 2] = rec.z;
    }
}

// ---------------------------------------------------------------------------
// Kernel 2: radius search + exact K-smallest selection. One wave per center.
// ---------------------------------------------------------------------------
__global__ __launch_bounds__(256) void radius_kernel(
    const float* __restrict__ pos,
    const float* __restrict__ pos_s,
    int* __restrict__ nbr_ws, int* __restrict__ nvalid_ws)
{
    __shared__ float d2L[4][CAP];
    __shared__ int   idL[4][CAP];
    __shared__ int   cntL[4];

    const int wv = threadIdx.x >> 6, lane = threadIdx.x & 63;
    const int c = blockIdx.x * 4 + wv;
    const int b = c >> 10;
    const float RSQ = 0.0225f;

    if (lane == 0) cntL[wv] = 0;

    float cx = pos_s[c * 3 + 0];
    float cy = pos_s[c * 3 + 1];
    float cz = pos_s[c * 3 + 2];
    const float* pb = pos + (size_t)b * NN * 3;

    for (int it = 0; it < NN / 64; ++it) {
        int p = it * 64 + lane;
        float dx = __fsub_rn(cx, pb[p * 3 + 0]);
        float dy = __fsub_rn(cy, pb[p * 3 + 1]);
        float dz = __fsub_rn(cz, pb[p * 3 + 2]);
        float d2 = __fadd_rn(__fadd_rn(__fmul_rn(dx, dx), __fmul_rn(dy, dy)),
                             __fmul_rn(dz, dz));
        if (d2 <= RSQ) {
            int slot = atomicAdd(&cntL[wv], 1);
            if (slot < CAP) { d2L[wv][slot] = d2; idL[wv][slot] = p; }
        }
    }
    int n = cntL[wv];
    if (n > CAP) n = CAP;

    if (n <= KNB) {
        if (lane == 0) nvalid_ws[c] = n;
        if (lane < n) nbr_ws[c * KNB + lane] = idL[wv][lane];
    } else {
        if (lane == 0) nvalid_ws[c] = KNB;
        for (int a = lane; a < n; a += 64) {
            float da = d2L[wv][a]; int ia = idL[wv][a];
            int r = 0;
            for (int jj = 0; jj < n; ++jj) {
                float dj = d2L[wv][jj]; int ij = idL[wv][jj];
                r += (dj < da || (dj == da && ij < ia)) ? 1 : 0;
            }
            if (r < KNB) nbr_ws[c * KNB + r] = ia;
        }
    }
}

// ---------------------------------------------------------------------------
// Kernel 3: message build -> 68x68 MLP x2 -> masked max-agg -> 68x128 matvec.
// ---------------------------------------------------------------------------
__device__ __forceinline__ float angle3(float ax, float ay, float az,
                                        float bx, float by, float bz)
{
    float cx = ay * bz - az * by;
    float cy = az * bx - ax * bz;
    float cz = ax * by - ay * bx;
    float cn = sqrtf(cx * cx + cy * cy + cz * cz);
    float dt = ax * bx + ay * by + az * bz;
    return atan2f(cn, dt);
}

__device__ __forceinline__ float4 fma4(float m, float4 w, float4 a)
{
    a.x = fmaf(m, w.x, a.x);
    a.y = fmaf(m, w.y, a.y);
    a.z = fmaf(m, w.z, a.z);
    a.w = fmaf(m, w.w, a.w);
    return a;
}

__device__ __forceinline__ void layer_pass(const float* __restrict__ inL,
                                           const float* __restrict__ Ws,
                                           const float* __restrict__ bs,
                                           float* __restrict__ outL, int t)
{
    const int e = t & 63, wvi = t >> 6;
    const bool has5 = (wvi == 0);
    const int j0 = wvi * 4, j1 = (wvi + 4) * 4, j2 = (wvi + 8) * 4,
              j3 = (wvi + 12) * 4, j4 = 64;

    float4 a0 = *reinterpret_cast<const float4*>(bs + j0);
    float4 a1 = *reinterpret_cast<const float4*>(bs + j1);
    float4 a2 = *reinterpret_cast<const float4*>(bs + j2);
    float4 a3 = *reinterpret_cast<const float4*>(bs + j3);
    float4 a4 = has5 ? *reinterpret_cast<const float4*>(bs + j4)
                     : make_float4(0.f, 0.f, 0.f, 0.f);

    const float* row = inL + e * 69;
#pragma unroll 4
    for (int i = 0; i < DIM; ++i) {
        float m = row[i];
        const float* wr = Ws + i * DIM;
        a0 = fma4(m, *reinterpret_cast<const float4*>(wr + j0), a0);
        a1 = fma4(m, *reinterpret_cast<const float4*>(wr + j1), a1);
        a2 = fma4(m, *reinterpret_cast<const float4*>(wr + j2), a2);
        a3 = fma4(m, *reinterpret_cast<const float4*>(wr + j3), a3);
        if (has5) a4 = fma4(m, *reinterpret_cast<const float4*>(wr + j4), a4);
    }

    float* orow = outL + e * 69;
    orow[j0 + 0] = fmaxf(a0.x, 0.f); orow[j0 + 1] = fmaxf(a0.y, 0.f);
    orow[j0 + 2] = fmaxf(a0.z, 0.f); orow[j0 + 3] = fmaxf(a0.w, 0.f);
    orow[j1 + 0] = fmaxf(a1.x, 0.f); orow[j1 + 1] = fmaxf(a1.y, 0.f);
    orow[j1 + 2] = fmaxf(a1.z, 0.f); orow[j1 + 3] = fmaxf(a1.w, 0.f);
    orow[j2 + 0] = fmaxf(a2.x, 0.f); orow[j2 + 1] = fmaxf(a2.y, 0.f);
    orow[j2 + 2] = fmaxf(a2.z, 0.f); orow[j2 + 3] = fmaxf(a2.w, 0.f);
    orow[j3 + 0] = fmaxf(a3.x, 0.f); orow[j3 + 1] = fmaxf(a3.y, 0.f);
    orow[j3 + 2] = fmaxf(a3.z, 0.f); orow[j3 + 3] = fmaxf(a3.w, 0.f);
    if (has5) {
        orow[64] = fmaxf(a4.x, 0.f); orow[65] = fmaxf(a4.y, 0.f);
        orow[66] = fmaxf(a4.z, 0.f); orow[67] = fmaxf(a4.w, 0.f);
    }
}

__global__ __launch_bounds__(256) void mlp_kernel(
    const float* __restrict__ x, const float* __restrict__ pos,
    const float* __restrict__ norm,
    const float* __restrict__ W1, const float* __restrict__ b1,
    const float* __restrict__ W2, const float* __restrict__ b2,
    const float* __restrict__ W3, const float* __restrict__ b3,
    const int* __restrict__ idx_ws, const float* __restrict__ pos_s,
    const int* __restrict__ nbr_ws, const int* __restrict__ nvalid_ws,
    float* __restrict__ out)
{
    __shared__ alignas(16) float W1s[DIM * DIM];
    __shared__ alignas(16) float W2s[DIM * DIM];
    __shared__ alignas(16) float b1s[DIM];
    __shared__ alignas(16) float b2s[DIM];
    __shared__ float msgL[64 * 69];
    __shared__ float h1L[64 * 69];
    __shared__ float aggL[2 * DIM];
    __shared__ int   nvL[2], jLs[64];

    const int t = threadIdx.x;
    const int cg0 = blockIdx.x * 2;

    for (int u = t; u < DIM * DIM; u += 256) { W1s[u] = W1[u]; W2s[u] = W2[u]; }
    if (t < DIM) { b1s[t] = b1[t]; b2s[t] = b2[t]; }
    if (t < 2) nvL[t] = min(nvalid_ws[cg0 + t], KNB);
    __syncthreads();

    const int e = t & 63, fc = t >> 6;
    const int lc = e >> 5, slot = e & 31;
    const int c = cg0 + lc;
    const int b = c >> 10;

    if (fc == 0) {
        int nv = nvL[lc];
        jLs[e] = (slot < nv) ? nbr_ws[c * KNB + slot] : 0;
    }
    __syncthreads();

    const int j = jLs[e];
    {
        const float* xj = x + ((size_t)b * NN + j) * NIN + fc * 16;
#pragma unroll
        for (int r = 0; r < 4; ++r) {
            float4 v = *reinterpret_cast<const float4*>(xj + r * 4);
            msgL[e * 69 + fc * 16 + r * 4 + 0] = v.x;
            msgL[e * 69 + fc * 16 + r * 4 + 1] = v.y;
            msgL[e * 69 + fc * 16 + r * 4 + 2] = v.z;
            msgL[e * 69 + fc * 16 + r * 4 + 3] = v.w;
        }
    }
    if (fc == 0) {
        float pix = pos_s[c * 3 + 0];
        float piy = pos_s[c * 3 + 1];
        float piz = pos_s[c * 3 + 2];
        int ic = idx_ws[c];
        const float* pj_ = pos  + ((size_t)b * NN + j) * 3;
        const float* nj_ = norm + ((size_t)b * NN + j) * 3;
        const float* ni_ = norm + ((size_t)b * NN + ic) * 3;
        float dx = pj_[0] - pix, dy = pj_[1] - piy, dz = pj_[2] - piz;
        float nix = ni_[0], niy = ni_[1], niz = ni_[2];
        float njx = nj_[0], njy = nj_[1], njz = nj_[2];
        msgL[e * 69 + 64] = sqrtf(dx * dx + dy * dy + dz * dz);
        msgL[e * 69 + 65] = angle3(nix, niy, niz, dx, dy, dz);
        msgL[e * 69 + 66] = angle3(njx, njy, njz, dx, dy, dz);
        msgL[e * 69 + 67] = angle3(nix, niy, niz, njx, njy, njz);
    }
    __syncthreads();

    layer_pass(msgL, W1s, b1s, h1L, t);
    __syncthreads();
    layer_pass(h1L, W2s, b2s, msgL, t);
    __syncthreads();

    if (t < 2 * DIM) {
        int cc = t / DIM, jf = t % DIM;
        int nv = nvL[cc];
        float v = -INFINITY;
        for (int s = 0; s < nv; ++s)
            v = fmaxf(v, msgL[(cc * 32 + s) * 69 + jf]);
        aggL[cc * DIM + jf] = v;
    }
    __syncthreads();

    {
        int cc = t >> 7, o = t & 127;
        int cgl = cg0 + cc;
        float acc = b3[o];
#pragma unroll 4
        for (int i = 0; i < DIM; ++i)
            acc = fmaf(aggL[cc * DIM + i], W3[i * NOUTF + o], acc);
        out[(size_t)cgl * NOUTF + o] = fmaxf(acc, 0.0f);
    }
}

// ---------------------------------------------------------------------------
extern "C" void kernel_launch(void* const* d_in, const int* in_sizes, int n_in,
                              void* d_out, int out_size, void* d_ws, size_t ws_size,
                              hipStream_t stream)
{
    const float* x    = (const float*)d_in[0];
    const float* pos  = (const float*)d_in[1];
    const float* norm = (const float*)d_in[2];
    const float* W1 = (const float*)d_in[4];
    const float* b1 = (const float*)d_in[5];
    const float* W2 = (const float*)d_in[6];
    const float* b2 = (const float*)d_in[7];
    const float* W3 = (const float*)d_in[8];
    const float* b3 = (const float*)d_in[9];

    float* out       = (float*)d_out;
    float* out_pos_s = out + (size_t)BB * MM * NOUTF;
    float* out_idx   = out_pos_s + (size_t)BB * MM * 3;

    char* ws = (char*)d_ws;
    int*   idx_ws    = (int*)ws;
    int*   nbr_ws    = (int*)(ws + 131072);
    int*   nvalid_ws = (int*)(ws + 131072 + (size_t)BB * MM * KNB * 4);

    fps_kernel<<<dim3(BB), dim3(256), 0, stream>>>(pos, idx_ws,
                                                   out_pos_s, out_idx);
    radius_kernel<<<dim3((BB * MM) / 4), dim3(256), 0, stream>>>(pos, out_pos_s,
                                                                 nbr_ws, nvalid_ws);
    mlp_kernel<<<dim3((BB * MM) / 2), dim3(256), 0, stream>>>(
        x, pos, norm, W1, b1, W2, b2, W3, b3,
        idx_ws, out_pos_s, nbr_ws, nvalid_ws, out);
}